// Round 5
// baseline (202.571 us; speedup 1.0000x reference)
//
#include <hip/hip_runtime.h>
#include <stdint.h>

typedef short bf16x8 __attribute__((ext_vector_type(8)));
typedef float f32x4 __attribute__((ext_vector_type(4)));

#define NROWS 16384
#define K1DIM 256
#define N1DIM 2048
#define N2DIM 96
#define MARGIN 0.03f

#define GLD16(g, l) __builtin_amdgcn_global_load_lds( \
    (const __attribute__((address_space(1))) uint32_t*)(g), \
    (__attribute__((address_space(3))) uint32_t*)(l), 16, 0, 0)

__device__ __forceinline__ ushort f2bf(float x) {
  union { float f; uint32_t u; } c; c.f = x;
  uint32_t u = c.u;
  return (ushort)((u + 0x7FFFu + ((u >> 16) & 1u)) >> 16);
}

// ---------------- K0: convert inputs to bf16 (x2, Wl1^T, W2sel^T, Wb1^T) ---
__global__ __launch_bounds__(256) void k0_convert(
    const float* __restrict__ bd, const float* __restrict__ Wl1,
    const float* __restrict__ Wl2, const float* __restrict__ Wb1,
    ushort* __restrict__ x2bf, ushort* __restrict__ wl1t,
    ushort* __restrict__ w2t, ushort* __restrict__ wb1t) {
  int i = blockIdx.x * 256 + threadIdx.x;
  if (i < NROWS * 256) x2bf[i] = f2bf(bd[i]);
  if (i < 2048 * 256) {  // wl1t[n][k] = Wl1[k][n]
    int n = i >> 8, k = i & 255;
    wl1t[i] = f2bf(Wl1[k * 2048 + n]);
  }
  if (i < 96 * 2048) {   // w2t[j][k] = Wl2[k][colmap(j)]
    int j = i >> 11, k = i & 2047;
    int col = (j < 48) ? j : (1440 + j);
    w2t[i] = f2bf(Wl2[k * 1536 + col]);
  }
  if (i < 512 * 128) {   // wb1t[j][m] = Wb1[m][j]
    int j = i >> 7, m = i & 127;
    wb1t[i] = f2bf(Wb1[m * 512 + j]);
  }
}

// ---------------- K1a: branch scores via bf16 MFMA -------------------------
__global__ __launch_bounds__(256) void k1a_score(
    const ushort* __restrict__ x2bf, const ushort* __restrict__ wb1t,
    const float* __restrict__ bb1, const float* __restrict__ Wb2,
    float* __restrict__ part) {
  __shared__ __align__(1024) ushort As[128 * 64];
  __shared__ __align__(1024) ushort Bs[128 * 64];
  const int t = threadIdx.x, ln = t & 63, wv = t >> 6;
  const int m0 = blockIdx.y << 7;
  const int n0 = blockIdx.x << 7;
  const int wm = (wv >> 1) << 6, wn = (wv & 1) << 6;
  const int rsub = ln >> 3, kc8 = ln & 7;
  const int q = ln >> 4, rr = ln & 15;

  f32x4 acc[4][4] = {};

  for (int k0 = 0; k0 < 128; k0 += 64) {
#pragma unroll
    for (int i = 0; i < 4; i++) {
      int inst = (wv << 2) + i;
      int row = (inst << 3) + rsub;
      GLD16(x2bf + (size_t)(m0 + row) * 256 + k0 + (kc8 << 3), As + (inst << 9));
      GLD16(wb1t + (size_t)(n0 + row) * 128 + k0 + (kc8 << 3), Bs + (inst << 9));
    }
    __syncthreads();
#pragma unroll
    for (int kk = 0; kk < 2; kk++) {
      int kb = ((kk << 2) + q) << 3;
      bf16x8 af[4], bfr[4];
#pragma unroll
      for (int mi = 0; mi < 4; mi++)
        af[mi] = *(const bf16x8*)(As + (((wm + (mi << 4) + rr)) << 6) + kb);
#pragma unroll
      for (int ni = 0; ni < 4; ni++)
        bfr[ni] = *(const bf16x8*)(Bs + (((wn + (ni << 4) + rr)) << 6) + kb);
#pragma unroll
      for (int mi = 0; mi < 4; mi++)
#pragma unroll
        for (int ni = 0; ni < 4; ni++)
          acc[mi][ni] = __builtin_amdgcn_mfma_f32_16x16x32_bf16(
              af[mi], bfr[ni], acc[mi][ni], 0, 0, 0);
    }
    __syncthreads();
  }

  float s4[4][4] = {};
#pragma unroll
  for (int ni = 0; ni < 4; ni++) {
    int col = n0 + wn + (ni << 4) + rr;
    float bias = bb1[col];
    float wdv = Wb2[col * 2 + 1] - Wb2[col * 2];
#pragma unroll
    for (int mi = 0; mi < 4; mi++) {
      f32x4 a = acc[mi][ni];
#pragma unroll
      for (int v = 0; v < 4; v++)
        s4[mi][v] += fmaxf(a[v] + bias, 0.f) * wdv;
    }
  }
#pragma unroll
  for (int off = 1; off <= 8; off <<= 1)
#pragma unroll
    for (int mi = 0; mi < 4; mi++)
#pragma unroll
      for (int v = 0; v < 4; v++)
        s4[mi][v] += __shfl_xor(s4[mi][v], off);

  if (rr == 0) {
    float* dst = part + (size_t)(blockIdx.x * 2 + (wv & 1)) * NROWS +
                 m0 + wm + (q << 2);
#pragma unroll
    for (int mi = 0; mi < 4; mi++) {
      float4 v4 = make_float4(s4[mi][0], s4[mi][1], s4[mi][2], s4[mi][3]);
      *(float4*)(dst + (mi << 4)) = v4;
    }
  }
}

// ---------------- K1b: sum partials, classify, compact marginal rows -------
__global__ __launch_bounds__(256) void k1b_classify(
    const float* __restrict__ part, const float* __restrict__ bb2,
    int* __restrict__ router, int* __restrict__ list, int* __restrict__ counter) {
  int t = blockIdx.x * 256 + threadIdx.x;
  float s = bb2[1] - bb2[0];
#pragma unroll
  for (int i = 0; i < 8; i++) s += part[i * NROWS + t];
  router[t] = (s >= 0.f) ? 1 : 0;
  if (fabsf(s) < MARGIN) {
    int idx = atomicAdd(counter, 1);
    list[idx] = t;
  }
}

// ---------------- K1c: exact fp32 recheck of marginal rows -----------------
__global__ __launch_bounds__(256) void k1c_recheck(
    const float* __restrict__ bd, const float* __restrict__ Wb1,
    const float* __restrict__ Wb2, const float* __restrict__ bb1,
    const float* __restrict__ bb2, const int* __restrict__ list,
    const int* __restrict__ counter, int* __restrict__ router) {
  const int ln = threadIdx.x & 63;
  const int wid = (blockIdx.x * 256 + threadIdx.x) >> 6;
  const int count = *counter;
  const float c = bb2[1] - bb2[0];

  for (int base = wid * 4; base < count; base += 512 * 4) {
    int rows[4];
#pragma unroll
    for (int r = 0; r < 4; r++) {
      int idx = base + r;
      rows[r] = list[(idx < count) ? idx : base];
    }
    float acc[4][8];
#pragma unroll
    for (int r = 0; r < 4; r++)
#pragma unroll
      for (int u = 0; u < 8; u++) acc[r][u] = 0.f;

    for (int m = 0; m < 128; m++) {
      float w[8];
#pragma unroll
      for (int u = 0; u < 8; u++) w[u] = Wb1[m * 512 + (u << 6) + ln];
#pragma unroll
      for (int r = 0; r < 4; r++) {
        float x = bd[(size_t)rows[r] * 256 + m];
#pragma unroll
        for (int u = 0; u < 8; u++) acc[r][u] = fmaf(x, w[u], acc[r][u]);
      }
    }
    float sc[4];
#pragma unroll
    for (int r = 0; r < 4; r++) {
      float s = 0.f;
#pragma unroll
      for (int u = 0; u < 8; u++) {
        int j = (u << 6) + ln;
        float wd = Wb2[j * 2 + 1] - Wb2[j * 2];
        s += fmaxf(acc[r][u] + bb1[j], 0.f) * wd;
      }
#pragma unroll
      for (int off = 1; off <= 32; off <<= 1) s += __shfl_xor(s, off);
      sc[r] = s + c;
    }
    if (ln == 0) {
#pragma unroll
      for (int r = 0; r < 4; r++)
        if (base + r < count) router[rows[r]] = (sc[r] >= 0.f) ? 1 : 0;
    }
  }
}

// ---------------- K2: FUSED GEMM1+GEMM2+select, 128-row blocks -------------
// block: 128 rows x 512 cols (quarter). Per 128-col chunk:
//   G1: m97 geometry (2x2 waves, 4x4 acc each) -> 128x128 H tile
//   H tile -> bf16 -> Hs (aliased onto dead As+Bs space, 16-slot XOR swizzle)
//   G2: accP[2][6] += Hs @ Ws
// Epilogue: select leaf by router, atomicAdd quarter-partial into zeroed out.
__global__ __launch_bounds__(256, 2) void k2_fused(
    const ushort* __restrict__ x2bf, const ushort* __restrict__ wl1t,
    const ushort* __restrict__ w2t, const float* __restrict__ bl1,
    const float* __restrict__ bl2, const int* __restrict__ router,
    float* __restrict__ out) {
  __shared__ __align__(1024) ushort U[16384];    // As(8K) + Bs(8K) <-> Hs(16K)
  __shared__ __align__(1024) ushort Wsm[12288];  // 96 x 128, swizzled
  ushort* As = U;
  ushort* Bs = U + 8192;
  ushort* Hs = U;
  const int t = threadIdx.x, ln = t & 63, wv = t >> 6;
  const int ks2 = blockIdx.x;       // col quarter: 0..3
  const int m0 = blockIdx.y << 7;   // 128-row block
  const int q = ln >> 4, rr = ln & 15;
  const int wm = (wv >> 1) << 6, wn = (wv & 1) << 6;
  const int r8 = ln >> 3, s8 = ln & 7;     // staging for [rows][64] tiles
  const int r16 = ln >> 4, s16 = ln & 15;  // staging for [rows][128] tiles

  f32x4 accP[2][6] = {};

  for (int nc = 0; nc < 4; nc++) {
    const int n0 = (ks2 << 9) + (nc << 7);

    // stage Ws: w2t[0..96)[n0..n0+128), swizzled slot = s ^ (row&15)
#pragma unroll
    for (int j = 0; j < 6; j++) {
      int inst = wv * 6 + j;              // 0..23, 4 rows each
      int r = (inst << 2) + r16;
      GLD16(w2t + (size_t)r * 2048 + n0 + ((s16 ^ (r & 15)) << 3),
            Wsm + (inst << 9));
    }

    f32x4 acc1[4][4] = {};
    for (int k0 = 0; k0 < K1DIM; k0 += 64) {
#pragma unroll
      for (int i = 0; i < 4; i++) {
        int inst = (wv << 2) + i;         // 0..15, 8 rows each
        int r = (inst << 3) + r8;
        GLD16(x2bf + (size_t)(m0 + r) * K1DIM + k0 + ((s8 ^ (r & 7)) << 3),
              As + (inst << 9));
        GLD16(wl1t + (size_t)(n0 + r) * K1DIM + k0 + ((s8 ^ (r & 7)) << 3),
              Bs + (inst << 9));
      }
      __syncthreads();
#pragma unroll
      for (int kk = 0; kk < 2; kk++) {
        int c = (kk << 2) + q;
        bf16x8 af[4], bfr[4];
#pragma unroll
        for (int mi = 0; mi < 4; mi++)
          af[mi] = *(const bf16x8*)(As + ((wm + (mi << 4) + rr) << 6) +
                                    ((c ^ (rr & 7)) << 3));
#pragma unroll
        for (int ni = 0; ni < 4; ni++)
          bfr[ni] = *(const bf16x8*)(Bs + ((wn + (ni << 4) + rr) << 6) +
                                     ((c ^ (rr & 7)) << 3));
#pragma unroll
        for (int mi = 0; mi < 4; mi++)
#pragma unroll
          for (int ni = 0; ni < 4; ni++)
            acc1[mi][ni] = __builtin_amdgcn_mfma_f32_16x16x32_bf16(
                af[mi], bfr[ni], acc1[mi][ni], 0, 0, 0);
      }
      __syncthreads();
    }

    // epilogue 1: bias + relu -> bf16 -> Hs (As/Bs dead; barrier above covers)
#pragma unroll
    for (int ni = 0; ni < 4; ni++) {
      int col = wn + (ni << 4) + rr;
      float bias = bl1[n0 + col];
#pragma unroll
      for (int mi = 0; mi < 4; mi++) {
        f32x4 a = acc1[mi][ni];
#pragma unroll
        for (int v = 0; v < 4; v++) {
          int row = wm + (mi << 4) + (q << 2) + v;
          int s = (col >> 3) ^ (row & 15);
          Hs[(row << 7) + (s << 3) + (col & 7)] = f2bf(fmaxf(a[v] + bias, 0.f));
        }
      }
    }
    __syncthreads();

    // G2: accP[g][96] += Hs[wave rows] @ Ws   (K=128 chunk)
#pragma unroll
    for (int kk = 0; kk < 4; kk++) {
      int c = (kk << 2) + q;
      bf16x8 ha[2];
#pragma unroll
      for (int g = 0; g < 2; g++) {
        int row = (wv << 5) + (g << 4) + rr;
        ha[g] = *(const bf16x8*)(Hs + (row << 7) + ((c ^ rr) << 3));
      }
#pragma unroll
      for (int ni = 0; ni < 6; ni++) {
        int row = (ni << 4) + rr;
        bf16x8 wb = *(const bf16x8*)(Wsm + (row << 7) + ((c ^ rr) << 3));
#pragma unroll
        for (int g = 0; g < 2; g++)
          accP[g][ni] = __builtin_amdgcn_mfma_f32_16x16x32_bf16(
              ha[g], wb, accP[g][ni], 0, 0, 0);
      }
    }
    __syncthreads();
  }

  // fused select epilogue: wave owns rows m0 + wv*32 + g*16 + ...
#pragma unroll
  for (int g = 0; g < 2; g++) {
    int rowb = m0 + (wv << 5) + (g << 4) + (q << 2);
#pragma unroll
    for (int v = 0; v < 4; v++) {
      int row = rowb + v;
      int sel = router[row];
      float v0 = sel ? accP[g][3][v] : accP[g][0][v];
      float v1 = sel ? accP[g][4][v] : accP[g][1][v];
      float v2 = sel ? accP[g][5][v] : accP[g][2][v];
      if (ks2 == 0) {  // add bias exactly once
        int bb = sel ? 1488 : 0;
        v0 += bl2[bb + rr];
        v1 += bl2[bb + 16 + rr];
        v2 += bl2[bb + 32 + rr];
      }
      float* ob = out + (size_t)row * 48 + rr;
      atomicAdd(ob, v0);
      atomicAdd(ob + 16, v1);
      atomicAdd(ob + 32, v2);
    }
  }
}

extern "C" void kernel_launch(void* const* d_in, const int* in_sizes, int n_in,
                              void* d_out, int out_size, void* d_ws, size_t ws_size,
                              hipStream_t stream) {
  const float* bd  = (const float*)d_in[0];
  const float* Wl1 = (const float*)d_in[1];
  const float* bl1 = (const float*)d_in[2];
  const float* Wl2 = (const float*)d_in[3];
  const float* bl2 = (const float*)d_in[4];
  const float* Wb1 = (const float*)d_in[5];
  const float* bb1 = (const float*)d_in[6];
  const float* Wb2 = (const float*)d_in[7];
  const float* bb2 = (const float*)d_in[8];

  char* ws = (char*)d_ws;
  ushort* x2bf  = (ushort*)(ws);                  // 16384*256*2  = 8,388,608
  ushort* wl1t  = (ushort*)(ws + 8388608);        // 2048*256*2   = 1,048,576
  ushort* w2t   = (ushort*)(ws + 9437184);        // 96*2048*2    =   393,216
  int*    router= (int*)(ws + 89522176);          // 16384*4
  ushort* wb1t  = (ushort*)(ws + 89587712);       // 512*128*2
  float*  part  = (float*)(ws + 89718784);        // 8*16384*4
  int*    list  = (int*)(ws + 90243072);          // 16384*4
  int*    counter=(int*)(ws + 90308608);          // 4
  float*  outp  = (float*)d_out;

  k0_convert<<<dim3(16384), dim3(256), 0, stream>>>(bd, Wl1, Wl2, Wb1,
                                                    x2bf, wl1t, w2t, wb1t);
  hipMemsetAsync(counter, 0, 4, stream);
  hipMemsetAsync(outp, 0, (size_t)out_size * 4, stream);
  k1a_score<<<dim3(4, 128), dim3(256), 0, stream>>>(x2bf, wb1t, bb1, Wb2, part);
  k1b_classify<<<dim3(64), dim3(256), 0, stream>>>(part, bb2, router, list, counter);
  k1c_recheck<<<dim3(128), dim3(256), 0, stream>>>(bd, Wb1, Wb2, bb1, bb2,
                                                   list, counter, router);
  k2_fused<<<dim3(4, 128), dim3(256), 0, stream>>>(x2bf, wl1t, w2t, bl1, bl2,
                                                   router, outp);
}

// Round 6
// 170.804 us; speedup vs baseline: 1.1860x; 1.1860x over previous
//
#include <hip/hip_runtime.h>
#include <stdint.h>

typedef short bf16x8 __attribute__((ext_vector_type(8)));
typedef float f32x4 __attribute__((ext_vector_type(4)));

#define NROWS 16384
#define K1DIM 256
#define N1DIM 2048
#define N2DIM 96
#define MARGIN 0.03f

#define GLD16(g, l) __builtin_amdgcn_global_load_lds( \
    (const __attribute__((address_space(1))) uint32_t*)(g), \
    (__attribute__((address_space(3))) uint32_t*)(l), 16, 0, 0)

__device__ __forceinline__ ushort f2bf(float x) {
  union { float f; uint32_t u; } c; c.f = x;
  uint32_t u = c.u;
  return (ushort)((u + 0x7FFFu + ((u >> 16) & 1u)) >> 16);
}

// ---------------- K0: convert inputs to bf16 (vectorized x2 path) ----------
__global__ __launch_bounds__(256) void k0_convert(
    const float* __restrict__ bd, const float* __restrict__ Wl1,
    const float* __restrict__ Wl2, const float* __restrict__ Wb1,
    ushort* __restrict__ x2bf, ushort* __restrict__ wl1t,
    ushort* __restrict__ w2t, ushort* __restrict__ wb1t) {
  int i = blockIdx.x * 256 + threadIdx.x;  // grid 4096 -> i < 1,048,576
  {
    float4 v = ((const float4*)bd)[i];
    ushort4 o;
    o.x = f2bf(v.x); o.y = f2bf(v.y); o.z = f2bf(v.z); o.w = f2bf(v.w);
    ((ushort4*)x2bf)[i] = o;
  }
  if (i < 2048 * 256) {  // wl1t[n][k] = Wl1[k][n]
    int n = i >> 8, k = i & 255;
    wl1t[i] = f2bf(Wl1[k * 2048 + n]);
  }
  if (i < 96 * 2048) {   // w2t[j][k] = Wl2[k][colmap(j)]
    int j = i >> 11, k = i & 2047;
    int col = (j < 48) ? j : (1440 + j);
    w2t[i] = f2bf(Wl2[k * 1536 + col]);
  }
  if (i < 512 * 128) {   // wb1t[j][m] = Wb1[m][j]
    int j = i >> 7, m = i & 127;
    wb1t[i] = f2bf(Wb1[m * 512 + j]);
  }
}

// ---------------- K1a: branch scores via bf16 MFMA -------------------------
__global__ __launch_bounds__(256) void k1a_score(
    const ushort* __restrict__ x2bf, const ushort* __restrict__ wb1t,
    const float* __restrict__ bb1, const float* __restrict__ Wb2,
    float* __restrict__ part) {
  __shared__ __align__(1024) ushort As[128 * 64];
  __shared__ __align__(1024) ushort Bs[128 * 64];
  const int t = threadIdx.x, ln = t & 63, wv = t >> 6;
  const int m0 = blockIdx.y << 7;
  const int n0 = blockIdx.x << 7;
  const int wm = (wv >> 1) << 6, wn = (wv & 1) << 6;
  const int rsub = ln >> 3, kc8 = ln & 7;
  const int q = ln >> 4, rr = ln & 15;

  f32x4 acc[4][4] = {};

  for (int k0 = 0; k0 < 128; k0 += 64) {
#pragma unroll
    for (int i = 0; i < 4; i++) {
      int inst = (wv << 2) + i;
      int row = (inst << 3) + rsub;
      GLD16(x2bf + (size_t)(m0 + row) * 256 + k0 + (kc8 << 3), As + (inst << 9));
      GLD16(wb1t + (size_t)(n0 + row) * 128 + k0 + (kc8 << 3), Bs + (inst << 9));
    }
    __syncthreads();
#pragma unroll
    for (int kk = 0; kk < 2; kk++) {
      int kb = ((kk << 2) + q) << 3;
      bf16x8 af[4], bfr[4];
#pragma unroll
      for (int mi = 0; mi < 4; mi++)
        af[mi] = *(const bf16x8*)(As + (((wm + (mi << 4) + rr)) << 6) + kb);
#pragma unroll
      for (int ni = 0; ni < 4; ni++)
        bfr[ni] = *(const bf16x8*)(Bs + (((wn + (ni << 4) + rr)) << 6) + kb);
#pragma unroll
      for (int mi = 0; mi < 4; mi++)
#pragma unroll
        for (int ni = 0; ni < 4; ni++)
          acc[mi][ni] = __builtin_amdgcn_mfma_f32_16x16x32_bf16(
              af[mi], bfr[ni], acc[mi][ni], 0, 0, 0);
    }
    __syncthreads();
  }

  float s4[4][4] = {};
#pragma unroll
  for (int ni = 0; ni < 4; ni++) {
    int col = n0 + wn + (ni << 4) + rr;
    float bias = bb1[col];
    float wdv = Wb2[col * 2 + 1] - Wb2[col * 2];
#pragma unroll
    for (int mi = 0; mi < 4; mi++) {
      f32x4 a = acc[mi][ni];
#pragma unroll
      for (int v = 0; v < 4; v++)
        s4[mi][v] += fmaxf(a[v] + bias, 0.f) * wdv;
    }
  }
#pragma unroll
  for (int off = 1; off <= 8; off <<= 1)
#pragma unroll
    for (int mi = 0; mi < 4; mi++)
#pragma unroll
      for (int v = 0; v < 4; v++)
        s4[mi][v] += __shfl_xor(s4[mi][v], off);

  if (rr == 0) {
    float* dst = part + (size_t)(blockIdx.x * 2 + (wv & 1)) * NROWS +
                 m0 + wm + (q << 2);
#pragma unroll
    for (int mi = 0; mi < 4; mi++) {
      float4 v4 = make_float4(s4[mi][0], s4[mi][1], s4[mi][2], s4[mi][3]);
      *(float4*)(dst + (mi << 4)) = v4;
    }
  }
}

// ---------------- K1b: sum partials, classify, compact marginal rows -------
__global__ __launch_bounds__(256) void k1b_classify(
    const float* __restrict__ part, const float* __restrict__ bb2,
    int* __restrict__ router, int* __restrict__ list, int* __restrict__ counter) {
  int t = blockIdx.x * 256 + threadIdx.x;
  float s = bb2[1] - bb2[0];
#pragma unroll
  for (int i = 0; i < 8; i++) s += part[i * NROWS + t];
  router[t] = (s >= 0.f) ? 1 : 0;
  if (fabsf(s) < MARGIN) {
    int idx = atomicAdd(counter, 1);
    list[idx] = t;
  }
}

// ---------------- K1c: exact fp32 recheck of marginal rows -----------------
__global__ __launch_bounds__(256) void k1c_recheck(
    const float* __restrict__ bd, const float* __restrict__ Wb1,
    const float* __restrict__ Wb2, const float* __restrict__ bb1,
    const float* __restrict__ bb2, const int* __restrict__ list,
    const int* __restrict__ counter, int* __restrict__ router) {
  const int ln = threadIdx.x & 63;
  const int wid = (blockIdx.x * 256 + threadIdx.x) >> 6;
  const int count = *counter;
  const float c = bb2[1] - bb2[0];

  for (int base = wid * 4; base < count; base += 512 * 4) {
    int rows[4];
#pragma unroll
    for (int r = 0; r < 4; r++) {
      int idx = base + r;
      rows[r] = list[(idx < count) ? idx : base];
    }
    float acc[4][8];
#pragma unroll
    for (int r = 0; r < 4; r++)
#pragma unroll
      for (int u = 0; u < 8; u++) acc[r][u] = 0.f;

    for (int m = 0; m < 128; m++) {
      float w[8];
#pragma unroll
      for (int u = 0; u < 8; u++) w[u] = Wb1[m * 512 + (u << 6) + ln];
#pragma unroll
      for (int r = 0; r < 4; r++) {
        float x = bd[(size_t)rows[r] * 256 + m];
#pragma unroll
        for (int u = 0; u < 8; u++) acc[r][u] = fmaf(x, w[u], acc[r][u]);
      }
    }
    float sc[4];
#pragma unroll
    for (int r = 0; r < 4; r++) {
      float s = 0.f;
#pragma unroll
      for (int u = 0; u < 8; u++) {
        int j = (u << 6) + ln;
        float wd = Wb2[j * 2 + 1] - Wb2[j * 2];
        s += fmaxf(acc[r][u] + bb1[j], 0.f) * wd;
      }
#pragma unroll
      for (int off = 1; off <= 32; off <<= 1) s += __shfl_xor(s, off);
      sc[r] = s + c;
    }
    if (ln == 0) {
#pragma unroll
      for (int r = 0; r < 4; r++)
        if (base + r < count) router[rows[r]] = (sc[r] >= 0.f) ? 1 : 0;
    }
  }
}

// ---------------- K2: FUSED GEMM1+GEMM2+select, K-step=128 -----------------
// block: 64 rows x 1024-col half, grid (2,256) (L2-friendly: 2MB x2/XCD).
// Per 128-col chunk: G1 in 2 K-steps of 128 (As 16K + Bs 32K staged/step),
// Hs (16K, aliased on Bs) -> G2 accP[6]. 6 barriers/chunk (vs 10 in R4).
__global__ __launch_bounds__(256, 2) void k2_fused(
    const ushort* __restrict__ x2bf, const ushort* __restrict__ wl1t,
    const ushort* __restrict__ w2t, const float* __restrict__ bl1,
    const float* __restrict__ bl2, const int* __restrict__ router,
    float* __restrict__ out) {
  __shared__ __align__(1024) ushort Bsm[16384];  // Bs[128x128] <-> Hs[64x128]
  __shared__ __align__(1024) ushort Asm[8192];   // As[64x128]
  __shared__ __align__(1024) ushort Wsm[12288];  // Ws[96x128]
  ushort* Hs = Bsm;
  const int t = threadIdx.x, ln = t & 63, wv = t >> 6;
  const int ks2 = blockIdx.x;       // n-half: 0,1
  const int m0 = blockIdx.y << 6;   // 64-row block
  const int q = ln >> 4, rr = ln & 15;
  const int sr4 = ln >> 4;          // staging: row-within-4
  const int s16 = ln & 15;          // staging: slot 0..15

  f32x4 accP[6] = {};

  for (int nc = 0; nc < 8; nc++) {
    const int n0 = (ks2 << 10) + (nc << 7);

    // stage Ws: w2t[0..96)[n0..n0+128), slot s holds chunk s^(r&7)
#pragma unroll
    for (int j = 0; j < 6; j++) {
      int inst = wv * 6 + j;        // 0..23, 4 rows each
      int r = (inst << 2) + sr4;
      int c = s16 ^ (r & 7);
      GLD16(w2t + (size_t)r * 2048 + n0 + (c << 3), Wsm + (inst << 9));
    }

    f32x4 acc1[4][2] = {};
#pragma unroll 1
    for (int ks = 0; ks < 2; ks++) {
      const int kg = ks << 7;
      // stage As[64x128]: 16 insts, 4/wave
#pragma unroll
      for (int i = 0; i < 4; i++) {
        int inst = (wv << 2) + i;
        int r = (inst << 2) + sr4;
        int c = s16 ^ (r & 7);
        GLD16(x2bf + (size_t)(m0 + r) * K1DIM + kg + (c << 3),
              Asm + (inst << 9));
      }
      // stage Bs[128x128]: 32 insts, 8/wave
#pragma unroll
      for (int i = 0; i < 8; i++) {
        int inst = (wv << 3) + i;
        int r = (inst << 2) + sr4;
        int c = s16 ^ (r & 7);
        GLD16(wl1t + (size_t)(n0 + r) * K1DIM + kg + (c << 3),
              Bsm + (inst << 9));
      }
      __syncthreads();
#pragma unroll
      for (int kk = 0; kk < 4; kk++) {
        int c = (kk << 2) + q;
        int sl = (c ^ (rr & 7)) << 3;
        bf16x8 af[4], bfr[2];
#pragma unroll
        for (int mi = 0; mi < 4; mi++)
          af[mi] = *(const bf16x8*)(Asm + (((mi << 4) + rr) << 7) + sl);
#pragma unroll
        for (int ni = 0; ni < 2; ni++)
          bfr[ni] = *(const bf16x8*)(Bsm + (((wv << 5) + (ni << 4) + rr) << 7) + sl);
#pragma unroll
        for (int mi = 0; mi < 4; mi++)
#pragma unroll
          for (int ni = 0; ni < 2; ni++)
            acc1[mi][ni] = __builtin_amdgcn_mfma_f32_16x16x32_bf16(
                af[mi], bfr[ni], acc1[mi][ni], 0, 0, 0);
      }
      __syncthreads();
    }

    // epilogue 1: bias + relu -> bf16 -> Hs (aliased on Bs; R4-verified swizzle)
#pragma unroll
    for (int ni = 0; ni < 2; ni++) {
      int col = (wv << 5) + (ni << 4) + rr;
      float bias = bl1[n0 + col];
#pragma unroll
      for (int mi = 0; mi < 4; mi++) {
        f32x4 a = acc1[mi][ni];
#pragma unroll
        for (int v = 0; v < 4; v++) {
          int row = (mi << 4) + (q << 2) + v;
          Hs[(row << 7) + (((col >> 3) ^ (row & 15)) << 3) + (col & 7)] =
              f2bf(fmaxf(a[v] + bias, 0.f));
        }
      }
    }
    __syncthreads();

    // G2: accP[wave's 16 rows][96] += Hs @ Ws (K=128 chunk)
#pragma unroll
    for (int kk = 0; kk < 4; kk++) {
      int cH = (kk << 2) + q;
      bf16x8 ha = *(const bf16x8*)(Hs + (((wv << 4) + rr) << 7) +
                                   ((cH ^ rr) << 3));
#pragma unroll
      for (int ni = 0; ni < 6; ni++) {
        bf16x8 wb = *(const bf16x8*)(Wsm + (((ni << 4) + rr) << 7) +
                                     ((cH ^ (rr & 7)) << 3));
        accP[ni] = __builtin_amdgcn_mfma_f32_16x16x32_bf16(ha, wb, accP[ni], 0, 0, 0);
      }
    }
    __syncthreads();
  }

  // fused select epilogue: wave owns rows m0+16*wv .. +15 (this n-half partial)
  {
    int rowb = m0 + (wv << 4) + (q << 2);
#pragma unroll
    for (int v = 0; v < 4; v++) {
      int row = rowb + v;
      int sel = router[row];
      float v0 = sel ? accP[3][v] : accP[0][v];
      float v1 = sel ? accP[4][v] : accP[1][v];
      float v2 = sel ? accP[5][v] : accP[2][v];
      if (ks2 == 0) {  // add bias exactly once
        int bb = sel ? 1488 : 0;
        v0 += bl2[bb + rr];
        v1 += bl2[bb + 16 + rr];
        v2 += bl2[bb + 32 + rr];
      }
      float* ob = out + (size_t)row * 48 + rr;
      atomicAdd(ob, v0);
      atomicAdd(ob + 16, v1);
      atomicAdd(ob + 32, v2);
    }
  }
}

extern "C" void kernel_launch(void* const* d_in, const int* in_sizes, int n_in,
                              void* d_out, int out_size, void* d_ws, size_t ws_size,
                              hipStream_t stream) {
  const float* bd  = (const float*)d_in[0];
  const float* Wl1 = (const float*)d_in[1];
  const float* bl1 = (const float*)d_in[2];
  const float* Wl2 = (const float*)d_in[3];
  const float* bl2 = (const float*)d_in[4];
  const float* Wb1 = (const float*)d_in[5];
  const float* bb1 = (const float*)d_in[6];
  const float* Wb2 = (const float*)d_in[7];
  const float* bb2 = (const float*)d_in[8];

  char* ws = (char*)d_ws;
  ushort* x2bf  = (ushort*)(ws);                  // 16384*256*2  = 8,388,608
  ushort* wl1t  = (ushort*)(ws + 8388608);        // 2048*256*2   = 1,048,576
  ushort* w2t   = (ushort*)(ws + 9437184);        // 96*2048*2    =   393,216
  int*    router= (int*)(ws + 89522176);          // 16384*4
  ushort* wb1t  = (ushort*)(ws + 89587712);       // 512*128*2
  float*  part  = (float*)(ws + 89718784);        // 8*16384*4
  int*    list  = (int*)(ws + 90243072);          // 16384*4
  int*    counter=(int*)(ws + 90308608);          // 4
  float*  outp  = (float*)d_out;

  k0_convert<<<dim3(4096), dim3(256), 0, stream>>>(bd, Wl1, Wl2, Wb1,
                                                   x2bf, wl1t, w2t, wb1t);
  hipMemsetAsync(counter, 0, 4, stream);
  hipMemsetAsync(outp, 0, (size_t)out_size * 4, stream);
  k1a_score<<<dim3(4, 128), dim3(256), 0, stream>>>(x2bf, wb1t, bb1, Wb2, part);
  k1b_classify<<<dim3(64), dim3(256), 0, stream>>>(part, bb2, router, list, counter);
  k1c_recheck<<<dim3(128), dim3(256), 0, stream>>>(bd, Wb1, Wb2, bb1, bb2,
                                                   list, counter, router);
  k2_fused<<<dim3(2, 256), dim3(256), 0, stream>>>(x2bf, wl1t, w2t, bl1, bl2,
                                                   router, outp);
}